// Round 2
// baseline (220.340 us; speedup 1.0000x reference)
//
#include <hip/hip_runtime.h>
#include <math.h>

// YOLO loss on MI355X. prediction (N,7,7,30) f32, target (N,7,7,25) f32.
// LDS-staged: coalesced float4 global->LDS, then per-thread struct reads from LDS.
constexpr int TOT   = 16384 * 7 * 7;      // 802816 cells
constexpr int TILE  = 256;                // cells per block
constexpr int NBLK  = TOT / TILE;         // 3136, exact
constexpr float INV_N = 1.0f / 16384.0f;

__device__ __forceinline__ float iou_f(float tx1,float ty1,float tx2,float ty2,
                                       float bx1,float by1,float bx2,float by2)
{
    float xi1 = fmaxf(tx1, bx1), yi1 = fmaxf(ty1, by1);
    float xi2 = fminf(tx2, bx2), yi2 = fminf(ty2, by2);
    float inter = fmaxf(xi2 - xi1, 0.0f) * fmaxf(yi2 - yi1, 0.0f);
    float a1 = (tx2 - tx1) * (ty2 - ty1);
    float a2 = (bx2 - bx1) * (by2 - by1);
    return inter / (a1 + a2 - inter + 1e-6f);
}

__global__ __launch_bounds__(256) void yolo_partial(
    const float* __restrict__ pred, const float* __restrict__ tgt,
    float* __restrict__ acc /* 5 f32, pre-zeroed */)
{
    // 256*30 + 256*25 floats = 3520 float4 = 56320 B
    __shared__ float4 smem4[3520];
    float* pred_s = (float*)smem4;          // 7680 floats
    float* tgt_s  = pred_s + TILE * 30;     // 6400 floats

    const int t    = threadIdx.x;
    const int base = blockIdx.x * TILE;

    // coalesced staging: tile bases are 16B-aligned (256*120 and 256*100 both %16==0)
    const float4* gp = reinterpret_cast<const float4*>(pred + (long)base * 30);
    const float4* gt = reinterpret_cast<const float4*>(tgt  + (long)base * 25);
    float4* sp = smem4;          // 1920 float4
    float4* st = smem4 + 1920;   // 1600 float4
#pragma unroll
    for (int i = 0; i < 7; ++i) sp[t + i * 256] = gp[t + i * 256];
    if (t < 128) sp[t + 1792] = gp[t + 1792];
#pragma unroll
    for (int i = 0; i < 6; ++i) st[t + i * 256] = gt[t + i * 256];
    if (t < 64) st[t + 1536] = gt[t + 1536];
    __syncthreads();

    const int   cell = base + t;
    const int   col  = cell % 7;
    const int   row  = (cell / 7) % 7;
    const float fcol = (float)col, frow = (float)row;

    float pv[30];
    {
        const float* p = pred_s + t * 30;
#pragma unroll
        for (int k = 0; k < 30; ++k) pv[k] = p[k];
    }
    float tv[25];
    {
        const float* tp = tgt_s + t * 25;
#pragma unroll
        for (int k = 0; k < 25; ++k) tv[k] = tp[k];
    }

    const float conf  = tv[4];
    const bool  noobj = (conf == 0.0f);

    // target abs corners, scaled by conf (reference: _rel2abs(target)*conf)
    float xc = (tv[0] + fcol) / 7.0f, yc = (tv[1] + frow) / 7.0f;
    float hw = tv[2] * 0.5f,          hh = tv[3] * 0.5f;
    float tx1 = (xc - hw) * conf, ty1 = (yc - hh) * conf;
    float tx2 = (xc + hw) * conf, ty2 = (yc + hh) * conf;

    // pred box 1
    float xc1 = (pv[0] + fcol) / 7.0f, yc1 = (pv[1] + frow) / 7.0f;
    float hw1 = pv[2] * 0.5f,          hh1 = pv[3] * 0.5f;
    float iou1 = iou_f(tx1, ty1, tx2, ty2,
                       xc1 - hw1, yc1 - hh1, xc1 + hw1, yc1 + hh1);
    // pred box 2
    float xc2 = (pv[5] + fcol) / 7.0f, yc2 = (pv[6] + frow) / 7.0f;
    float hw2 = pv[7] * 0.5f,          hh2 = pv[8] * 0.5f;
    float iou2 = iou_f(tx1, ty1, tx2, ty2,
                       xc2 - hw2, yc2 - hh2, xc2 + hw2, yc2 + hh2);

    // NB: reference as written picks box2 when iou1 > iou2
    const bool pick2 = iou1 > iou2;
    float hx  = pick2 ? pv[5] : pv[0];
    float hy  = pick2 ? pv[6] : pv[1];
    float hwv = pick2 ? pv[7] : pv[2];
    float hhv = pick2 ? pv[8] : pv[3];
    float hc  = pick2 ? pv[9] : pv[4];

    float a_xy, a_wh, a_co, a_cn, a_cl;
    // loss_xy
    float px = noobj ? 0.0f : fmaxf(hx, 0.0f);
    float py = noobj ? 0.0f : fmaxf(hy, 0.0f);
    float dx = tv[0] - px, dy = tv[1] - py;
    a_xy = dx * dx + dy * dy;
    // loss_wh (sum of squares; sqrt in finalize)
    float pw = noobj ? 0.0f : fmaxf(hwv, 0.0f);
    float ph = noobj ? 0.0f : fmaxf(hhv, 0.0f);
    float dw = tv[2] - pw, dh = tv[3] - ph;
    a_wh = dw * dw + dh * dh;
    // conf losses
    float cc = fminf(fmaxf(hc, 0.0f), 1.0f);
    float co = noobj ? 0.0f : cc;
    float cn = noobj ? cc : 0.0f;
    float dco = conf - co, dcn = conf - cn;
    a_co = dco * dco;
    a_cn = dcn * dcn;
    // class loss
    float cl = 0.0f;
#pragma unroll
    for (int k = 0; k < 20; ++k) {
        float pc = noobj ? 0.0f : pv[10 + k];
        float d  = tv[5 + k] - pc;
        cl += d * d;
    }
    a_cl = cl;

    // wave64 butterfly reduce
#pragma unroll
    for (int off = 32; off > 0; off >>= 1) {
        a_xy += __shfl_down(a_xy, off);
        a_wh += __shfl_down(a_wh, off);
        a_co += __shfl_down(a_co, off);
        a_cn += __shfl_down(a_cn, off);
        a_cl += __shfl_down(a_cl, off);
    }
    __shared__ float red[4][5];
    const int lane = t & 63;
    const int wid  = t >> 6;
    if (lane == 0) {
        red[wid][0] = a_xy; red[wid][1] = a_wh; red[wid][2] = a_co;
        red[wid][3] = a_cn; red[wid][4] = a_cl;
    }
    __syncthreads();
    if (t == 0) {
        float s0 = red[0][0] + red[1][0] + red[2][0] + red[3][0];
        float s1 = red[0][1] + red[1][1] + red[2][1] + red[3][1];
        float s2 = red[0][2] + red[1][2] + red[2][2] + red[3][2];
        float s3 = red[0][3] + red[1][3] + red[2][3] + red[3][3];
        float s4 = red[0][4] + red[1][4] + red[2][4] + red[3][4];
        atomicAdd(&acc[0], s0);
        atomicAdd(&acc[1], s1);
        atomicAdd(&acc[2], s2);
        atomicAdd(&acc[3], s3);
        atomicAdd(&acc[4], s4);
    }
}

__global__ void yolo_final(const float* __restrict__ acc, float* __restrict__ out)
{
    if (threadIdx.x == 0 && blockIdx.x == 0) {
        float lxy = acc[0] * INV_N;
        float lwh = sqrtf(acc[1] + 1e-6f) * INV_N;
        float lco = acc[2] * INV_N;
        float lcn = acc[3] * INV_N;
        float lcl = acc[4] * INV_N;
        out[0] = lxy;
        out[1] = lwh;
        out[2] = lco;
        out[3] = lcn;
        out[4] = lcl;
        out[5] = 5.0f * lxy + 5.0f * lwh + lco + 0.5f * lcn + lcl;
    }
}

extern "C" void kernel_launch(void* const* d_in, const int* in_sizes, int n_in,
                              void* d_out, int out_size, void* d_ws, size_t ws_size,
                              hipStream_t stream)
{
    const float* pred = (const float*)d_in[0];
    const float* tgt  = (const float*)d_in[1];
    float* out = (float*)d_out;
    float* acc = (float*)d_ws;

    hipMemsetAsync(acc, 0, 5 * sizeof(float), stream);
    yolo_partial<<<NBLK, 256, 0, stream>>>(pred, tgt, acc);
    yolo_final<<<1, 64, 0, stream>>>(acc, out);
}

// Round 3
// 45.413 us; speedup vs baseline: 4.8520x; 4.8520x over previous
//
#include <hip/hip_runtime.h>
#include <math.h>

// YOLO loss on MI355X. prediction (N,7,7,30) f32, target (N,7,7,25) f32.
// Small-tile LDS staging: 64-thread blocks, 64-cell tiles (14 KB LDS) so
// ~11 blocks/CU stay resident and stage/compute phases overlap across blocks.
constexpr int TOT   = 16384 * 7 * 7;      // 802816 cells
constexpr int TILE  = 64;                 // cells per block
constexpr int NBLK  = TOT / TILE;         // 12544, exact
constexpr int NSLOT = 64;                 // spread accumulator slots
constexpr int SLOT_STRIDE = 32;           // floats (128 B) per slot -> own line
constexpr float INV_N = 1.0f / 16384.0f;

__device__ __forceinline__ float iou_f(float tx1,float ty1,float tx2,float ty2,
                                       float bx1,float by1,float bx2,float by2)
{
    float xi1 = fmaxf(tx1, bx1), yi1 = fmaxf(ty1, by1);
    float xi2 = fminf(tx2, bx2), yi2 = fminf(ty2, by2);
    float inter = fmaxf(xi2 - xi1, 0.0f) * fmaxf(yi2 - yi1, 0.0f);
    float a1 = (tx2 - tx1) * (ty2 - ty1);
    float a2 = (bx2 - bx1) * (by2 - by1);
    return inter / (a1 + a2 - inter + 1e-6f);
}

__global__ __launch_bounds__(64) void yolo_partial(
    const float* __restrict__ pred, const float* __restrict__ tgt,
    float* __restrict__ acc /* NSLOT*SLOT_STRIDE f32, pre-zeroed */)
{
    // 64*30 + 64*25 floats = 880 float4 = 14080 B
    __shared__ float4 smem4[880];
    float* pred_s = (float*)smem4;          // 1920 floats, stride 30
    float* tgt_s  = pred_s + TILE * 30;     // 1600 floats, stride 25

    const int t    = threadIdx.x;           // 0..63 (one wave)
    const int base = blockIdx.x * TILE;

    // coalesced staging; tile byte bases: 64*120 and 64*100 are both %16==0
    const float4* gp = reinterpret_cast<const float4*>(pred + (long)base * 30);
    const float4* gt = reinterpret_cast<const float4*>(tgt  + (long)base * 25);
    float4* sp = smem4;          // 480 float4
    float4* st = smem4 + 480;    // 400 float4
#pragma unroll
    for (int i = 0; i < 7; ++i) sp[t + i * 64] = gp[t + i * 64];
    if (t < 32) sp[t + 448] = gp[t + 448];
#pragma unroll
    for (int i = 0; i < 6; ++i) st[t + i * 64] = gt[t + i * 64];
    if (t < 16) st[t + 384] = gt[t + 384];
    __syncthreads();

    const int   cell = base + t;
    const int   col  = cell % 7;
    const int   row  = (cell / 7) % 7;
    const float fcol = (float)col, frow = (float)row;

    float pv[30];
    {
        const float* p = pred_s + t * 30;
#pragma unroll
        for (int k = 0; k < 30; ++k) pv[k] = p[k];
    }
    float tv[25];
    {
        const float* tp = tgt_s + t * 25;
#pragma unroll
        for (int k = 0; k < 25; ++k) tv[k] = tp[k];
    }

    const float conf  = tv[4];
    const bool  noobj = (conf == 0.0f);

    // target abs corners, scaled by conf (reference: _rel2abs(target)*conf)
    float xc = (tv[0] + fcol) / 7.0f, yc = (tv[1] + frow) / 7.0f;
    float hw = tv[2] * 0.5f,          hh = tv[3] * 0.5f;
    float tx1 = (xc - hw) * conf, ty1 = (yc - hh) * conf;
    float tx2 = (xc + hw) * conf, ty2 = (yc + hh) * conf;

    // pred box 1
    float xc1 = (pv[0] + fcol) / 7.0f, yc1 = (pv[1] + frow) / 7.0f;
    float hw1 = pv[2] * 0.5f,          hh1 = pv[3] * 0.5f;
    float iou1 = iou_f(tx1, ty1, tx2, ty2,
                       xc1 - hw1, yc1 - hh1, xc1 + hw1, yc1 + hh1);
    // pred box 2
    float xc2 = (pv[5] + fcol) / 7.0f, yc2 = (pv[6] + frow) / 7.0f;
    float hw2 = pv[7] * 0.5f,          hh2 = pv[8] * 0.5f;
    float iou2 = iou_f(tx1, ty1, tx2, ty2,
                       xc2 - hw2, yc2 - hh2, xc2 + hw2, yc2 + hh2);

    // NB: reference as written picks box2 when iou1 > iou2
    const bool pick2 = iou1 > iou2;
    float hx  = pick2 ? pv[5] : pv[0];
    float hy  = pick2 ? pv[6] : pv[1];
    float hwv = pick2 ? pv[7] : pv[2];
    float hhv = pick2 ? pv[8] : pv[3];
    float hc  = pick2 ? pv[9] : pv[4];

    float a_xy, a_wh, a_co, a_cn, a_cl;
    // loss_xy
    float px = noobj ? 0.0f : fmaxf(hx, 0.0f);
    float py = noobj ? 0.0f : fmaxf(hy, 0.0f);
    float dx = tv[0] - px, dy = tv[1] - py;
    a_xy = dx * dx + dy * dy;
    // loss_wh (sum of squares; sqrt in finalize)
    float pw = noobj ? 0.0f : fmaxf(hwv, 0.0f);
    float ph = noobj ? 0.0f : fmaxf(hhv, 0.0f);
    float dw = tv[2] - pw, dh = tv[3] - ph;
    a_wh = dw * dw + dh * dh;
    // conf losses
    float cc = fminf(fmaxf(hc, 0.0f), 1.0f);
    float co = noobj ? 0.0f : cc;
    float cn = noobj ? cc : 0.0f;
    float dco = conf - co, dcn = conf - cn;
    a_co = dco * dco;
    a_cn = dcn * dcn;
    // class loss
    float cl = 0.0f;
#pragma unroll
    for (int k = 0; k < 20; ++k) {
        float pc = noobj ? 0.0f : pv[10 + k];
        float d  = tv[5 + k] - pc;
        cl += d * d;
    }
    a_cl = cl;

    // wave64 butterfly reduce (block == one wave)
#pragma unroll
    for (int off = 32; off > 0; off >>= 1) {
        a_xy += __shfl_down(a_xy, off);
        a_wh += __shfl_down(a_wh, off);
        a_co += __shfl_down(a_co, off);
        a_cn += __shfl_down(a_cn, off);
        a_cl += __shfl_down(a_cl, off);
    }
    if (t == 0) {
        float* slot = acc + (blockIdx.x & (NSLOT - 1)) * SLOT_STRIDE;
        atomicAdd(&slot[0], a_xy);
        atomicAdd(&slot[1], a_wh);
        atomicAdd(&slot[2], a_co);
        atomicAdd(&slot[3], a_cn);
        atomicAdd(&slot[4], a_cl);
    }
}

__global__ __launch_bounds__(64) void yolo_final(
    const float* __restrict__ acc, float* __restrict__ out)
{
    const int l = threadIdx.x;  // 0..63, one slot each
    float s0 = acc[l * SLOT_STRIDE + 0];
    float s1 = acc[l * SLOT_STRIDE + 1];
    float s2 = acc[l * SLOT_STRIDE + 2];
    float s3 = acc[l * SLOT_STRIDE + 3];
    float s4 = acc[l * SLOT_STRIDE + 4];
#pragma unroll
    for (int off = 32; off > 0; off >>= 1) {
        s0 += __shfl_down(s0, off);
        s1 += __shfl_down(s1, off);
        s2 += __shfl_down(s2, off);
        s3 += __shfl_down(s3, off);
        s4 += __shfl_down(s4, off);
    }
    if (l == 0) {
        float lxy = s0 * INV_N;
        float lwh = sqrtf(s1 + 1e-6f) * INV_N;
        float lco = s2 * INV_N;
        float lcn = s3 * INV_N;
        float lcl = s4 * INV_N;
        out[0] = lxy;
        out[1] = lwh;
        out[2] = lco;
        out[3] = lcn;
        out[4] = lcl;
        out[5] = 5.0f * lxy + 5.0f * lwh + lco + 0.5f * lcn + lcl;
    }
}

extern "C" void kernel_launch(void* const* d_in, const int* in_sizes, int n_in,
                              void* d_out, int out_size, void* d_ws, size_t ws_size,
                              hipStream_t stream)
{
    const float* pred = (const float*)d_in[0];
    const float* tgt  = (const float*)d_in[1];
    float* out = (float*)d_out;
    float* acc = (float*)d_ws;

    hipMemsetAsync(acc, 0, NSLOT * SLOT_STRIDE * sizeof(float), stream);
    yolo_partial<<<NBLK, 64, 0, stream>>>(pred, tgt, acc);
    yolo_final<<<1, 64, 0, stream>>>(acc, out);
}